// Round 1
// baseline (177.380 us; speedup 1.0000x reference)
//
#include <hip/hip_runtime.h>

// Problem sizes (fixed by reference setup_inputs)
constexpr int Bsz = 32768;
constexpr int Hn  = 256;
constexpr int In  = 128;
constexpr long long BH = (long long)Bsz * Hn;

constexpr int BT = 64;    // batch rows per block
constexpr int KT = 32;    // K tile
constexpr int PA = 68;    // padded LDS stride for A tile (floats), 16B-aligned rows
constexpr int PW = 260;   // padded LDS stride for W tile (floats), 16B-aligned rows

// Accumulate acc[8][8] += A[rowBase+.., 0..K) @ W[h, 0..K)^T  over all K
// A: [Bsz][ldA] row-major, W: [Hn][ldW] row-major (ldW == K here)
// Block: 256 threads. Thread (tid): rows r0..r0+7 with r0=(tid>>5)*8,
// cols c0..c0+7 with c0=(tid&31)*8 (relative to tile / H).
__device__ __forceinline__ void gemm_accum(
    const float* __restrict__ A, int ldA, int K,
    const float* __restrict__ W, int ldW,
    int rowBase, int tid, float acc[8][8],
    float* __restrict__ As, float* __restrict__ Ws)
{
    const int r  = tid & 63;          // staging: row within tile (wave-contiguous)
    const int kq = (tid >> 6) * 8;    // staging: k offset (uniform per wave)
    const int r0 = (tid >> 5) * 8;
    const int c0 = (tid & 31) * 8;

    for (int ks = 0; ks < K; ks += KT) {
        __syncthreads();
        // ---- stage A tile: 64 rows x KT, transposed -> As[k][row] ----
        {
            const float* asrc = A + (size_t)(rowBase + r) * ldA + ks + kq;
            float4 p0 = *(const float4*)(asrc);
            float4 p1 = *(const float4*)(asrc + 4);
            As[(kq + 0) * PA + r] = p0.x;
            As[(kq + 1) * PA + r] = p0.y;
            As[(kq + 2) * PA + r] = p0.z;
            As[(kq + 3) * PA + r] = p0.w;
            As[(kq + 4) * PA + r] = p1.x;
            As[(kq + 5) * PA + r] = p1.y;
            As[(kq + 6) * PA + r] = p1.z;
            As[(kq + 7) * PA + r] = p1.w;
        }
        // ---- stage W tile: 256 rows (h) x KT, transposed -> Ws[k][h] ----
        {
            const float* wsrc = W + (size_t)tid * ldW + ks;
            #pragma unroll
            for (int b2 = 0; b2 < 2; ++b2) {
                float4 q0 = *(const float4*)(wsrc + b2 * 16 + 0);
                float4 q1 = *(const float4*)(wsrc + b2 * 16 + 4);
                float4 q2 = *(const float4*)(wsrc + b2 * 16 + 8);
                float4 q3 = *(const float4*)(wsrc + b2 * 16 + 12);
                int kb = b2 * 16;
                Ws[(kb + 0) * PW + tid] = q0.x;  Ws[(kb + 1) * PW + tid] = q0.y;
                Ws[(kb + 2) * PW + tid] = q0.z;  Ws[(kb + 3) * PW + tid] = q0.w;
                Ws[(kb + 4) * PW + tid] = q1.x;  Ws[(kb + 5) * PW + tid] = q1.y;
                Ws[(kb + 6) * PW + tid] = q1.z;  Ws[(kb + 7) * PW + tid] = q1.w;
                Ws[(kb + 8) * PW + tid] = q2.x;  Ws[(kb + 9) * PW + tid] = q2.y;
                Ws[(kb + 10) * PW + tid] = q2.z; Ws[(kb + 11) * PW + tid] = q2.w;
                Ws[(kb + 12) * PW + tid] = q3.x; Ws[(kb + 13) * PW + tid] = q3.y;
                Ws[(kb + 14) * PW + tid] = q3.z; Ws[(kb + 15) * PW + tid] = q3.w;
            }
        }
        __syncthreads();
        // ---- compute ----
        #pragma unroll 8
        for (int kk = 0; kk < KT; ++kk) {
            float4 a0 = *(const float4*)&As[kk * PA + r0];
            float4 a1 = *(const float4*)&As[kk * PA + r0 + 4];
            float4 w0 = *(const float4*)&Ws[kk * PW + c0];
            float4 w1 = *(const float4*)&Ws[kk * PW + c0 + 4];
            float av[8] = {a0.x, a0.y, a0.z, a0.w, a1.x, a1.y, a1.z, a1.w};
            float wv[8] = {w0.x, w0.y, w0.z, w0.w, w1.x, w1.y, w1.z, w1.w};
            #pragma unroll
            for (int ii = 0; ii < 8; ++ii)
                #pragma unroll
                for (int jj = 0; jj < 8; ++jj)
                    acc[ii][jj] = fmaf(av[ii], wv[jj], acc[ii][jj]);
        }
    }
}

// Kernel 1: coupling GEMM + spike + refractory -> z_new, v_new, rho_new
__global__ __launch_bounds__(256) void k_vcell(
    const float* __restrict__ v, const float* __restrict__ cur,
    const float* __restrict__ rho, const float* __restrict__ Gc,
    float* __restrict__ out)
{
    __shared__ float As[KT * PA];
    __shared__ float Ws[KT * PW];
    const int tid = threadIdx.x;
    const int rowBase = blockIdx.x * BT;

    float acc[8][8];
    #pragma unroll
    for (int a = 0; a < 8; ++a)
        #pragma unroll
        for (int b = 0; b < 8; ++b) acc[a][b] = 0.0f;

    gemm_accum(v, Hn, Hn, Gc, Hn, rowBase, tid, acc, As, Ws);

    const int r0 = (tid >> 5) * 8;
    const int c0 = (tid & 31) * 8;
    float* out_z   = out;
    float* out_v   = out + BH;
    float* out_rho = out + 3 * BH;

    #pragma unroll
    for (int rr = 0; rr < 8; ++rr) {
        const size_t base = (size_t)(rowBase + r0 + rr) * Hn + c0;
        float4 vv0 = *(const float4*)(v + base);
        float4 vv1 = *(const float4*)(v + base + 4);
        float4 ii0 = *(const float4*)(cur + base);
        float4 ii1 = *(const float4*)(cur + base + 4);
        float4 rh0 = *(const float4*)(rho + base);
        float4 rh1 = *(const float4*)(rho + base + 4);
        float vv[8] = {vv0.x, vv0.y, vv0.z, vv0.w, vv1.x, vv1.y, vv1.z, vv1.w};
        float ii[8] = {ii0.x, ii0.y, ii0.z, ii0.w, ii1.x, ii1.y, ii1.z, ii1.w};
        float rh[8] = {rh0.x, rh0.y, rh0.z, rh0.w, rh1.x, rh1.y, rh1.z, rh1.w};
        float zn[8], vn[8], rn[8];
        #pragma unroll
        for (int cc = 0; cc < 8; ++cc) {
            // dv = 0.1*((0 - v) + i) + coupling ; v_decayed = v + dv
            float dv   = 0.1f * ((0.0f - vv[cc]) + ii[cc]) + acc[rr][cc];
            float vdec = vv[cc] + dv;
            float z    = (vdec - 1.0f) > 0.0f ? 1.0f : 0.0f;
            float vnew = (1.0f - z) * vdec;              // V_RESET = 0
            float mask = rh[cc] > 0.0f ? 1.0f : 0.0f;
            vnew = (1.0f - mask) * vnew + mask * vv[cc];
            z    = (1.0f - mask) * z;
            float rhon = (1.0f - z) * fmaxf(rh[cc] - mask, 0.0f) + z * 5.0f;
            zn[cc] = z; vn[cc] = vnew; rn[cc] = rhon;
        }
        *(float4*)(out_z + base)       = make_float4(zn[0], zn[1], zn[2], zn[3]);
        *(float4*)(out_z + base + 4)   = make_float4(zn[4], zn[5], zn[6], zn[7]);
        *(float4*)(out_v + base)       = make_float4(vn[0], vn[1], vn[2], vn[3]);
        *(float4*)(out_v + base + 4)   = make_float4(vn[4], vn[5], vn[6], vn[7]);
        *(float4*)(out_rho + base)     = make_float4(rn[0], rn[1], rn[2], rn[3]);
        *(float4*)(out_rho + base + 4) = make_float4(rn[4], rn[5], rn[6], rn[7]);
    }
}

// Kernel 2: i_new = i*0.8 + x@Wi^T + z@Wr^T
__global__ __launch_bounds__(256) void k_icell(
    const float* __restrict__ x, const float* __restrict__ z,
    const float* __restrict__ cur, const float* __restrict__ Wi,
    const float* __restrict__ Wr, float* __restrict__ out)
{
    __shared__ float As[KT * PA];
    __shared__ float Ws[KT * PW];
    const int tid = threadIdx.x;
    const int rowBase = blockIdx.x * BT;

    float acc[8][8];
    #pragma unroll
    for (int a = 0; a < 8; ++a)
        #pragma unroll
        for (int b = 0; b < 8; ++b) acc[a][b] = 0.0f;

    gemm_accum(x, In, In, Wi, In, rowBase, tid, acc, As, Ws);
    gemm_accum(z, Hn, Hn, Wr, Hn, rowBase, tid, acc, As, Ws);

    const int r0 = (tid >> 5) * 8;
    const int c0 = (tid & 31) * 8;
    float* out_i = out + 2 * BH;

    #pragma unroll
    for (int rr = 0; rr < 8; ++rr) {
        const size_t base = (size_t)(rowBase + r0 + rr) * Hn + c0;
        float4 ii0 = *(const float4*)(cur + base);
        float4 ii1 = *(const float4*)(cur + base + 4);
        float ii[8] = {ii0.x, ii0.y, ii0.z, ii0.w, ii1.x, ii1.y, ii1.z, ii1.w};
        float on[8];
        #pragma unroll
        for (int cc = 0; cc < 8; ++cc) {
            float idec = ii[cc] + (-0.2f) * ii[cc];   // i + (-DT*TAU_SYN_INV)*i
            on[cc] = idec + acc[rr][cc];
        }
        *(float4*)(out_i + base)     = make_float4(on[0], on[1], on[2], on[3]);
        *(float4*)(out_i + base + 4) = make_float4(on[4], on[5], on[6], on[7]);
    }
}

extern "C" void kernel_launch(void* const* d_in, const int* in_sizes, int n_in,
                              void* d_out, int out_size, void* d_ws, size_t ws_size,
                              hipStream_t stream) {
    const float* x   = (const float*)d_in[0];  // input_tensor (B, I)
    const float* z   = (const float*)d_in[1];  // z            (B, H)
    const float* v   = (const float*)d_in[2];  // v            (B, H)
    const float* cur = (const float*)d_in[3];  // i            (B, H)
    const float* rho = (const float*)d_in[4];  // rho          (B, H)
    const float* Wi  = (const float*)d_in[5];  // input_weights     (H, I)
    const float* Wr  = (const float*)d_in[6];  // recurrent_weights (H, H)
    const float* Gc  = (const float*)d_in[7];  // g_coupling        (H, H)
    float* out = (float*)d_out;

    dim3 grid(Bsz / BT), block(256);
    hipLaunchKernelGGL(k_vcell, grid, block, 0, stream, v, cur, rho, Gc, out);
    hipLaunchKernelGGL(k_icell, grid, block, 0, stream, x, z, cur, Wi, Wr, out);
}

// Round 2
// 144.809 us; speedup vs baseline: 1.2249x; 1.2249x over previous
//
#include <hip/hip_runtime.h>

typedef __attribute__((ext_vector_type(8))) short bf16x8;
typedef __attribute__((ext_vector_type(4))) float f32x4;

constexpr int Bsz = 32768;
constexpr int Hn  = 256;
constexpr int In  = 128;
constexpr long long BH = (long long)Bsz * Hn;

constexpr int BT = 32;    // batch rows per block
constexpr int KT = 32;    // K tile (fp32 path)
constexpr int PA = 36;    // LDS stride A tile [k][row]
constexpr int PW = 260;   // LDS stride W tile [k][col]

// ---------------------------------------------------------------------------
// vcell: coupling GEMM (fp32, exact sequential-k order) + spike + refractory
// 256 threads; thread tile 8 rows x 4 cols: r0=(tid>>6)*8 (wave-uniform),
// c0=(tid&63)*4.
// ---------------------------------------------------------------------------
__global__ __launch_bounds__(256, 4) void k_vcell(
    const float* __restrict__ v, const float* __restrict__ cur,
    const float* __restrict__ rho, const float* __restrict__ Gc,
    float* __restrict__ out)
{
    __shared__ float As[KT * PA];
    __shared__ float Ws[KT * PW];
    const int tid = threadIdx.x;
    const int rowBase = blockIdx.x * BT;
    const int r0 = (tid >> 6) * 8;
    const int c0 = (tid & 63) * 4;

    float acc[8][4];
    #pragma unroll
    for (int a = 0; a < 8; ++a)
        #pragma unroll
        for (int b = 0; b < 4; ++b) acc[a][b] = 0.0f;

    const int sar = tid >> 3;        // stage-A row (0..31)
    const int sak = (tid & 7) * 4;   // stage-A k offset (0..28)

    for (int ks = 0; ks < Hn; ks += KT) {
        __syncthreads();
        // stage A (v) tile 32 rows x 32 k, transposed -> As[k][row]
        {
            float4 a4 = *(const float4*)(v + (size_t)(rowBase + sar) * Hn + ks + sak);
            As[(sak + 0) * PA + sar] = a4.x;
            As[(sak + 1) * PA + sar] = a4.y;
            As[(sak + 2) * PA + sar] = a4.z;
            As[(sak + 3) * PA + sar] = a4.w;
        }
        // stage W (Gc) tile 256 rows x 32 k, transposed -> Ws[k][col]
        {
            const float* wsrc = Gc + (size_t)tid * Hn + ks;
            #pragma unroll
            for (int j = 0; j < 8; ++j) {
                float4 w4 = *(const float4*)(wsrc + j * 4);
                Ws[(j * 4 + 0) * PW + tid] = w4.x;
                Ws[(j * 4 + 1) * PW + tid] = w4.y;
                Ws[(j * 4 + 2) * PW + tid] = w4.z;
                Ws[(j * 4 + 3) * PW + tid] = w4.w;
            }
        }
        __syncthreads();
        #pragma unroll 8
        for (int kk = 0; kk < KT; ++kk) {
            float4 a0 = *(const float4*)&As[kk * PA + r0];
            float4 a1 = *(const float4*)&As[kk * PA + r0 + 4];
            float4 w0 = *(const float4*)&Ws[kk * PW + c0];
            float av[8] = {a0.x, a0.y, a0.z, a0.w, a1.x, a1.y, a1.z, a1.w};
            float wv[4] = {w0.x, w0.y, w0.z, w0.w};
            #pragma unroll
            for (int ii = 0; ii < 8; ++ii)
                #pragma unroll
                for (int jj = 0; jj < 4; ++jj)
                    acc[ii][jj] = fmaf(av[ii], wv[jj], acc[ii][jj]);
        }
    }

    float* out_z   = out;
    float* out_v   = out + BH;
    float* out_rho = out + 3 * BH;

    #pragma unroll
    for (int rr = 0; rr < 8; ++rr) {
        const size_t base = (size_t)(rowBase + r0 + rr) * Hn + c0;
        float4 vv4 = *(const float4*)(v + base);
        float4 ii4 = *(const float4*)(cur + base);
        float4 rh4 = *(const float4*)(rho + base);
        float vv[4] = {vv4.x, vv4.y, vv4.z, vv4.w};
        float ii[4] = {ii4.x, ii4.y, ii4.z, ii4.w};
        float rh[4] = {rh4.x, rh4.y, rh4.z, rh4.w};
        float zn[4], vn[4], rn[4];
        #pragma unroll
        for (int cc = 0; cc < 4; ++cc) {
            float dv   = 0.1f * ((0.0f - vv[cc]) + ii[cc]) + acc[rr][cc];
            float vdec = vv[cc] + dv;
            float z    = (vdec - 1.0f) > 0.0f ? 1.0f : 0.0f;
            float vnew = (1.0f - z) * vdec;              // V_RESET = 0
            float mask = rh[cc] > 0.0f ? 1.0f : 0.0f;
            vnew = (1.0f - mask) * vnew + mask * vv[cc];
            z    = (1.0f - mask) * z;
            float rhon = (1.0f - z) * fmaxf(rh[cc] - mask, 0.0f) + z * 5.0f;
            zn[cc] = z; vn[cc] = vnew; rn[cc] = rhon;
        }
        *(float4*)(out_z + base)   = make_float4(zn[0], zn[1], zn[2], zn[3]);
        *(float4*)(out_v + base)   = make_float4(vn[0], vn[1], vn[2], vn[3]);
        *(float4*)(out_rho + base) = make_float4(rn[0], rn[1], rn[2], rn[3]);
    }
}

// ---------------------------------------------------------------------------
// icell: i_new = 0.8*i + x@Wi^T + z@Wr^T  via bf16 MFMA (tolerance-checked)
// 256 threads, 4 waves; block tile 32 rows x 256 cols; wave: 32r x 64c.
// LDS tiles bf16, XOR-swizzled: byte ^= ((row&7)<<4).
// ---------------------------------------------------------------------------
constexpr int IKT = 64;  // K tile in bf16 elements (128 B rows)

__device__ __forceinline__ unsigned short f2bf(float f) {
    unsigned int u = __float_as_uint(f);
    unsigned int r = (u + 0x7fffu + ((u >> 16) & 1u)) >> 16;   // RNE
    return (unsigned short)r;
}
__device__ __forceinline__ bf16x8 pack8(float4 lo, float4 hi) {
    bf16x8 r;
    r[0] = (short)f2bf(lo.x); r[1] = (short)f2bf(lo.y);
    r[2] = (short)f2bf(lo.z); r[3] = (short)f2bf(lo.w);
    r[4] = (short)f2bf(hi.x); r[5] = (short)f2bf(hi.y);
    r[6] = (short)f2bf(hi.z); r[7] = (short)f2bf(hi.w);
    return r;
}

__global__ __launch_bounds__(256, 4) void k_icell(
    const float* __restrict__ x, const float* __restrict__ z,
    const float* __restrict__ cur, const float* __restrict__ Wi,
    const float* __restrict__ Wr, float* __restrict__ out)
{
    __shared__ short Ab[32 * IKT];    // 4 KB  [row][k] bf16, swizzled
    __shared__ short Wb[256 * IKT];   // 32 KB [col][k] bf16, swizzled
    const int tid  = threadIdx.x;
    const int lane = tid & 63;
    const int wc   = (tid >> 6) * 64;        // wave's column base
    const int rowBase = blockIdx.x * BT;

    f32x4 acc[2][4];
    #pragma unroll
    for (int m = 0; m < 2; ++m)
        #pragma unroll
        for (int c = 0; c < 4; ++c) acc[m][c] = (f32x4){0.f, 0.f, 0.f, 0.f};

    const int ln = lane & 15, lg = lane >> 4;
    const int sar = tid >> 3;          // stage-A row (0..31)
    const int sak = (tid & 7) * 8;     // stage-A k offset (0..56)

    // two GEMM phases: (A=x, W=Wi, K=128) then (A=z, W=Wr, K=256)
    #pragma unroll 1
    for (int phase = 0; phase < 2; ++phase) {
        const float* A  = phase ? z : x;
        const float* W  = phase ? Wr : Wi;
        const int    K  = phase ? Hn : In;
        const int    ld = K;
        #pragma unroll 1
        for (int ks = 0; ks < K; ks += IKT) {
            __syncthreads();
            // stage A: 32 rows x 64 k fp32 -> bf16
            {
                const float* src = A + (size_t)(rowBase + sar) * ld + ks + sak;
                float4 f0 = *(const float4*)(src);
                float4 f1 = *(const float4*)(src + 4);
                int off = (sar * 128 + sak * 2) ^ ((sar & 7) << 4);
                *(bf16x8*)((char*)Ab + off) = pack8(f0, f1);
            }
            // stage W: 256 rows x 64 k fp32 -> bf16 (row = tid)
            {
                const float* wsrc = W + (size_t)tid * ld + ks;
                #pragma unroll
                for (int j = 0; j < 8; ++j) {
                    float4 f0 = *(const float4*)(wsrc + j * 8);
                    float4 f1 = *(const float4*)(wsrc + j * 8 + 4);
                    int off = (tid * 128 + j * 16) ^ ((tid & 7) << 4);
                    *(bf16x8*)((char*)Wb + off) = pack8(f0, f1);
                }
            }
            __syncthreads();
            // compute: 2 k-steps of 32, 2 row-frags, 4 col-frags
            #pragma unroll
            for (int s = 0; s < 2; ++s) {
                const int kb = s * 64 + lg * 16;
                bf16x8 a0 = *(const bf16x8*)((const char*)Ab +
                            ((ln * 128 + kb) ^ ((ln & 7) << 4)));
                bf16x8 a1 = *(const bf16x8*)((const char*)Ab +
                            (((ln + 16) * 128 + kb) ^ ((ln & 7) << 4)));
                #pragma unroll
                for (int c = 0; c < 4; ++c) {
                    const int col = wc + c * 16 + ln;
                    bf16x8 b = *(const bf16x8*)((const char*)Wb +
                               ((col * 128 + kb) ^ ((col & 7) << 4)));
                    acc[0][c] = __builtin_amdgcn_mfma_f32_16x16x32_bf16(a0, b, acc[0][c], 0, 0, 0);
                    acc[1][c] = __builtin_amdgcn_mfma_f32_16x16x32_bf16(a1, b, acc[1][c], 0, 0, 0);
                }
            }
        }
    }

    // epilogue: D mapping col = lane&15, row = (lane>>4)*4 + reg
    float* out_i = out + 2 * BH;
    #pragma unroll
    for (int m = 0; m < 2; ++m) {
        #pragma unroll
        for (int c = 0; c < 4; ++c) {
            const int col = wc + c * 16 + ln;
            const int rowb = rowBase + m * 16 + lg * 4;
            #pragma unroll
            for (int r = 0; r < 4; ++r) {
                const size_t idx = (size_t)(rowb + r) * Hn + col;
                out_i[idx] = 0.8f * cur[idx] + acc[m][c][r];
            }
        }
    }
}

extern "C" void kernel_launch(void* const* d_in, const int* in_sizes, int n_in,
                              void* d_out, int out_size, void* d_ws, size_t ws_size,
                              hipStream_t stream) {
    const float* x   = (const float*)d_in[0];
    const float* z   = (const float*)d_in[1];
    const float* v   = (const float*)d_in[2];
    const float* cur = (const float*)d_in[3];
    const float* rho = (const float*)d_in[4];
    const float* Wi  = (const float*)d_in[5];
    const float* Wr  = (const float*)d_in[6];
    const float* Gc  = (const float*)d_in[7];
    float* out = (float*)d_out;

    dim3 grid(Bsz / BT), block(256);
    hipLaunchKernelGGL(k_vcell, grid, block, 0, stream, v, cur, rho, Gc, out);
    hipLaunchKernelGGL(k_icell, grid, block, 0, stream, x, z, cur, Wi, Wr, out);
}